// Round 2
// baseline (545.891 us; speedup 1.0000x reference)
//
#include <hip/hip_runtime.h>
#include <hip/hip_bf16.h>

// MHA forward on MI355X: B=4, S=2048, H=16, D=64, HIDDEN=1024.
// Inputs/outputs are FLOAT32 (per reference dtypes). Internals use bf16 MFMA
// with fp32 accumulation; q/k/v/attn-out staged in workspace as bf16.
// Stage 1: QKV = x @ W^T + b  (NT GEMM, 128x128 tile, mfma_f32_16x16x32_bf16)
// Stage 2: flash attention per (b,h), 64-row Q tiles, online softmax
// Stage 3: out = attn @ Wo^T + bo  (fp32 output)

typedef __attribute__((ext_vector_type(8))) short short8;   // 8 x bf16 (4 VGPRs)
typedef __attribute__((ext_vector_type(4))) float floatx4;  // MFMA C/D

#define HID 1024
#define SEQ 2048
#define BATCH 4
#define NH 16
#define HD 64
#define M_TOT (BATCH * SEQ)   // 8192

#define BM 128
#define BN 128
#define BK 64
#define LDP 72                // padded LDS row stride (bf16 elems): 144 B

static __device__ __forceinline__ float bf2f(ushort u) {
    union { unsigned int i; float f; } v;
    v.i = ((unsigned int)u) << 16;
    return v.f;
}
static __device__ __forceinline__ ushort f2bf(float f) {
    union { float f; unsigned int u; } v;
    v.f = f;
    unsigned int u = v.u;
    unsigned int r = (u + 0x7fffu + ((u >> 16) & 1u)) >> 16;  // RNE
    return (ushort)r;
}
static __device__ __forceinline__ ushort4 f4tobf(float4 f) {
    ushort4 r;
    r.x = f2bf(f.x); r.y = f2bf(f.y); r.z = f2bf(f.z); r.w = f2bf(f.w);
    return r;
}

// ---------------------------------------------------------------------------
// Stage 1: QKV projection. A = x (fp32 [8192,1024]); W,bias fp32.
// grid.z in {0,1,2} selects (Wq,bq,q)/(Wk,bk,k)/(Wv,bv,v).
// Output bf16 in [B,H,S,D].
// ---------------------------------------------------------------------------
__global__ __launch_bounds__(256) void qkv_gemm(
    const float* __restrict__ A,
    const float* __restrict__ W0, const float* __restrict__ W1,
    const float* __restrict__ W2,
    const float* __restrict__ b0, const float* __restrict__ b1,
    const float* __restrict__ b2,
    ushort* __restrict__ o0, ushort* __restrict__ o1, ushort* __restrict__ o2)
{
    __shared__ ushort As[BM * LDP];
    __shared__ ushort Bs[BN * LDP];

    const int tid  = threadIdx.x;
    const int wave = tid >> 6;
    const int lane = tid & 63;
    const int l16  = lane & 15;
    const int lq   = lane >> 4;

    const int m0 = blockIdx.x * BM;
    const int n0 = blockIdx.y * BN;

    const int z = blockIdx.z;
    const float* W    = (z == 0) ? W0 : (z == 1) ? W1 : W2;
    const float* bias = (z == 0) ? b0 : (z == 1) ? b1 : b2;
    ushort* out       = (z == 0) ? o0 : (z == 1) ? o1 : o2;

    const int wm = (wave & 1) * 64;
    const int wn = (wave >> 1) * 64;

    floatx4 acc[4][4];
#pragma unroll
    for (int i = 0; i < 4; i++)
#pragma unroll
        for (int j = 0; j < 4; j++)
            acc[i][j] = (floatx4){0.f, 0.f, 0.f, 0.f};

    for (int k0 = 0; k0 < HID; k0 += BK) {
        __syncthreads();
        // A tile: 128 rows x 64 floats = 2048 float4 chunks, 8/thread
#pragma unroll
        for (int i = 0; i < 8; i++) {
            int c = i * 256 + tid;
            int row = c >> 4, ch = c & 15;
            float4 d = *(const float4*)(A + (size_t)(m0 + row) * HID + k0 + ch * 4);
            *(ushort4*)(&As[row * LDP + ch * 4]) = f4tobf(d);
        }
        // W tile
#pragma unroll
        for (int i = 0; i < 8; i++) {
            int c = i * 256 + tid;
            int row = c >> 4, ch = c & 15;
            float4 d = *(const float4*)(W + (size_t)(n0 + row) * HID + k0 + ch * 4);
            *(ushort4*)(&Bs[row * LDP + ch * 4]) = f4tobf(d);
        }
        __syncthreads();

#pragma unroll
        for (int kk = 0; kk < BK; kk += 32) {
            short8 a[4], b[4];
#pragma unroll
            for (int i = 0; i < 4; i++)
                a[i] = *(const short8*)(&As[(wm + i * 16 + l16) * LDP + kk + lq * 8]);
#pragma unroll
            for (int j = 0; j < 4; j++)
                b[j] = *(const short8*)(&Bs[(wn + j * 16 + l16) * LDP + kk + lq * 8]);
#pragma unroll
            for (int i = 0; i < 4; i++)
#pragma unroll
                for (int j = 0; j < 4; j++)
                    acc[i][j] = __builtin_amdgcn_mfma_f32_16x16x32_bf16(
                        a[i], b[j], acc[i][j], 0, 0, 0);
        }
    }

    // epilogue: C/D layout col = l16, row = lq*4 + r; out layout [B,H,S,D] bf16
#pragma unroll
    for (int j = 0; j < 4; j++) {
        int n = n0 + wn + j * 16 + l16;
        float bv = bias[n];
#pragma unroll
        for (int i = 0; i < 4; i++) {
#pragma unroll
            for (int r = 0; r < 4; r++) {
                int m = m0 + wm + i * 16 + lq * 4 + r;
                float val = acc[i][j][r] + bv;
                int b_ = m >> 11, s_ = m & (SEQ - 1);
                int h_ = n >> 6,  d_ = n & (HD - 1);
                out[(((size_t)b_ * NH + h_) * SEQ + s_) * HD + d_] = f2bf(val);
            }
        }
    }
}

// ---------------------------------------------------------------------------
// Stage 3: output projection. A = attn-out (bf16 [8192,1024]); Wo,bo fp32;
// out fp32 row-major.
// ---------------------------------------------------------------------------
__global__ __launch_bounds__(256) void proj_gemm(
    const ushort* __restrict__ A,
    const float* __restrict__ W,
    const float* __restrict__ bias,
    float* __restrict__ out)
{
    __shared__ ushort As[BM * LDP];
    __shared__ ushort Bs[BN * LDP];

    const int tid  = threadIdx.x;
    const int wave = tid >> 6;
    const int lane = tid & 63;
    const int l16  = lane & 15;
    const int lq   = lane >> 4;

    const int m0 = blockIdx.x * BM;
    const int n0 = blockIdx.y * BN;

    const int wm = (wave & 1) * 64;
    const int wn = (wave >> 1) * 64;

    floatx4 acc[4][4];
#pragma unroll
    for (int i = 0; i < 4; i++)
#pragma unroll
        for (int j = 0; j < 4; j++)
            acc[i][j] = (floatx4){0.f, 0.f, 0.f, 0.f};

    for (int k0 = 0; k0 < HID; k0 += BK) {
        __syncthreads();
        // A tile (bf16): 1024 16B-chunks, 4/thread
#pragma unroll
        for (int i = 0; i < 4; i++) {
            int c = i * 256 + tid;
            int row = c >> 3, ch = c & 7;
            uint4 d = *(const uint4*)(A + (size_t)(m0 + row) * HID + k0 + ch * 8);
            *(uint4*)(&As[row * LDP + ch * 8]) = d;
        }
        // W tile (fp32 -> bf16)
#pragma unroll
        for (int i = 0; i < 8; i++) {
            int c = i * 256 + tid;
            int row = c >> 4, ch = c & 15;
            float4 d = *(const float4*)(W + (size_t)(n0 + row) * HID + k0 + ch * 4);
            *(ushort4*)(&Bs[row * LDP + ch * 4]) = f4tobf(d);
        }
        __syncthreads();

#pragma unroll
        for (int kk = 0; kk < BK; kk += 32) {
            short8 a[4], b[4];
#pragma unroll
            for (int i = 0; i < 4; i++)
                a[i] = *(const short8*)(&As[(wm + i * 16 + l16) * LDP + kk + lq * 8]);
#pragma unroll
            for (int j = 0; j < 4; j++)
                b[j] = *(const short8*)(&Bs[(wn + j * 16 + l16) * LDP + kk + lq * 8]);
#pragma unroll
            for (int i = 0; i < 4; i++)
#pragma unroll
                for (int j = 0; j < 4; j++)
                    acc[i][j] = __builtin_amdgcn_mfma_f32_16x16x32_bf16(
                        a[i], b[j], acc[i][j], 0, 0, 0);
        }
    }

#pragma unroll
    for (int j = 0; j < 4; j++) {
        int n = n0 + wn + j * 16 + l16;
        float bv = bias[n];
#pragma unroll
        for (int i = 0; i < 4; i++) {
#pragma unroll
            for (int r = 0; r < 4; r++) {
                int m = m0 + wm + i * 16 + lq * 4 + r;
                out[(size_t)m * HID + n] = acc[i][j][r] + bv;
            }
        }
    }
}

// ---------------------------------------------------------------------------
// Stage 2: flash attention. One block = 64 Q rows of one (b,h).
// Q/K/V bf16 [B,H,S,D]; output bf16 [B,S,H*D].
// ---------------------------------------------------------------------------
__global__ __launch_bounds__(256) void attn_flash(
    const ushort* __restrict__ q, const ushort* __restrict__ k,
    const ushort* __restrict__ v, ushort* __restrict__ o)
{
    __shared__ ushort Ks[64 * LDP];  // K tile  [s_local][d]
    __shared__ ushort Vt[64 * LDP];  // V tile transposed [d][s_local]
    __shared__ ushort Ps[64 * LDP];  // P tile  [q_local][s_local]

    const int tid  = threadIdx.x;
    const int wave = tid >> 6;
    const int lane = tid & 63;
    const int l16  = lane & 15;
    const int lq   = lane >> 4;

    const int qb = blockIdx.x;   // 0..31
    const int bh = blockIdx.y;   // 0..63
    const int b_ = bh >> 4, h_ = bh & 15;

    const size_t base = (size_t)bh * SEQ * HD;
    const ushort* Q = q + base;
    const ushort* K = k + base;
    const ushort* V = v + base;

    const ushort* qrow = Q + (size_t)(qb * 64 + wave * 16 + l16) * HD;
    short8 qf[2];
    qf[0] = *(const short8*)(qrow + lq * 8);
    qf[1] = *(const short8*)(qrow + 32 + lq * 8);

    floatx4 o_acc[4];
#pragma unroll
    for (int jd = 0; jd < 4; jd++) o_acc[jd] = (floatx4){0.f, 0.f, 0.f, 0.f};
    float m_r[4] = {-INFINITY, -INFINITY, -INFINITY, -INFINITY};
    float l_r[4] = {0.f, 0.f, 0.f, 0.f};

    for (int t = 0; t < SEQ / 64; t++) {
        __syncthreads();
#pragma unroll
        for (int i = 0; i < 2; i++) {
            int c = i * 256 + tid;
            int row = c >> 3, ch = c & 7;
            uint4 d = *(const uint4*)(K + (size_t)(t * 64 + row) * HD + ch * 8);
            *(uint4*)(&Ks[row * LDP + ch * 8]) = d;
        }
#pragma unroll
        for (int i = 0; i < 2; i++) {
            int c = i * 256 + tid;
            int row = c >> 3, ch = c & 7;
            uint4 dd = *(const uint4*)(V + (size_t)(t * 64 + row) * HD + ch * 8);
            const ushort* pv = (const ushort*)&dd;
#pragma unroll
            for (int j2 = 0; j2 < 8; j2++)
                Vt[(ch * 8 + j2) * LDP + row] = pv[j2];
        }
        __syncthreads();

        floatx4 sacc[4];
#pragma unroll
        for (int j = 0; j < 4; j++) {
            sacc[j] = (floatx4){0.f, 0.f, 0.f, 0.f};
#pragma unroll
            for (int kk = 0; kk < 2; kk++) {
                short8 kf = *(const short8*)(&Ks[(j * 16 + l16) * LDP + kk * 32 + lq * 8]);
                sacc[j] = __builtin_amdgcn_mfma_f32_16x16x32_bf16(qf[kk], kf, sacc[j], 0, 0, 0);
            }
        }
#pragma unroll
        for (int j = 0; j < 4; j++)
#pragma unroll
            for (int r = 0; r < 4; r++) sacc[j][r] *= 0.125f;

        float mx[4];
#pragma unroll
        for (int r = 0; r < 4; r++)
            mx[r] = fmaxf(fmaxf(sacc[0][r], sacc[1][r]), fmaxf(sacc[2][r], sacc[3][r]));
#pragma unroll
        for (int off = 1; off < 16; off <<= 1)
#pragma unroll
            for (int r = 0; r < 4; r++)
                mx[r] = fmaxf(mx[r], __shfl_xor(mx[r], off, 64));

        float alpha[4];
#pragma unroll
        for (int r = 0; r < 4; r++) {
            float mn = fmaxf(m_r[r], mx[r]);
            alpha[r] = __expf(m_r[r] - mn);
            m_r[r] = mn;
        }
        float rs[4] = {0.f, 0.f, 0.f, 0.f};
#pragma unroll
        for (int j = 0; j < 4; j++)
#pragma unroll
            for (int r = 0; r < 4; r++) {
                float p = __expf(sacc[j][r] - m_r[r]);
                sacc[j][r] = p;
                rs[r] += p;
            }
#pragma unroll
        for (int off = 1; off < 16; off <<= 1)
#pragma unroll
            for (int r = 0; r < 4; r++) rs[r] += __shfl_xor(rs[r], off, 64);
#pragma unroll
        for (int r = 0; r < 4; r++) l_r[r] = l_r[r] * alpha[r] + rs[r];
#pragma unroll
        for (int jd = 0; jd < 4; jd++)
#pragma unroll
            for (int r = 0; r < 4; r++) o_acc[jd][r] *= alpha[r];

        // P (C-layout) -> Ps[q_local][s_local] (A-layout source)
#pragma unroll
        for (int j = 0; j < 4; j++)
#pragma unroll
            for (int r = 0; r < 4; r++)
                Ps[(wave * 16 + lq * 4 + r) * LDP + j * 16 + l16] = f2bf(sacc[j][r]);
        __syncthreads();

        short8 pf[2];
        pf[0] = *(const short8*)(&Ps[(wave * 16 + l16) * LDP + lq * 8]);
        pf[1] = *(const short8*)(&Ps[(wave * 16 + l16) * LDP + 32 + lq * 8]);
#pragma unroll
        for (int jd = 0; jd < 4; jd++) {
#pragma unroll
            for (int kk = 0; kk < 2; kk++) {
                short8 vf = *(const short8*)(&Vt[(jd * 16 + l16) * LDP + kk * 32 + lq * 8]);
                o_acc[jd] = __builtin_amdgcn_mfma_f32_16x16x32_bf16(pf[kk], vf, o_acc[jd], 0, 0, 0);
            }
        }
    }

#pragma unroll
    for (int jd = 0; jd < 4; jd++) {
#pragma unroll
        for (int r = 0; r < 4; r++) {
            int srow = qb * 64 + wave * 16 + lq * 4 + r;
            float val = o_acc[jd][r] / l_r[r];
            o[((size_t)b_ * SEQ + srow) * HID + h_ * HD + jd * 16 + l16] = f2bf(val);
        }
    }
}

// ---------------------------------------------------------------------------
extern "C" void kernel_launch(void* const* d_in, const int* in_sizes, int n_in,
                              void* d_out, int out_size, void* d_ws, size_t ws_size,
                              hipStream_t stream)
{
    const float* x  = (const float*)d_in[0];
    const float* Wq = (const float*)d_in[1];
    const float* bq = (const float*)d_in[2];
    const float* Wk = (const float*)d_in[3];
    const float* bk = (const float*)d_in[4];
    const float* Wv = (const float*)d_in[5];
    const float* bv = (const float*)d_in[6];
    const float* Wo = (const float*)d_in[7];
    const float* bo = (const float*)d_in[8];
    float* out = (float*)d_out;

    const size_t tensor_elems = (size_t)M_TOT * HID;  // 8,388,608
    ushort* qws = (ushort*)d_ws;
    ushort* kws = qws + tensor_elems;
    ushort* vws = kws + tensor_elems;
    ushort* aws = vws + tensor_elems;   // total 64 MiB bf16 in ws

    dim3 g1(M_TOT / BM, HID / BN, 3);
    qkv_gemm<<<g1, 256, 0, stream>>>(x, Wq, Wk, Wv, bq, bk, bv, qws, kws, vws);

    dim3 g2(SEQ / 64, BATCH * NH, 1);
    attn_flash<<<g2, 256, 0, stream>>>(qws, kws, vws, aws);

    dim3 g3(M_TOT / BM, HID / BN, 1);
    proj_gemm<<<g3, 256, 0, stream>>>(aws, Wo, bo, out);
}